// Round 1
// baseline (676.400 us; speedup 1.0000x reference)
//
#include <hip/hip_runtime.h>
#include <hip/hip_bf16.h>

// Problem constants (from reference): B=64, L=4096, D=512, fp32 in/out.
// context[b,d] = (1/L) * sum_l softmax_l(energy[b,:]) * enc[b,l,d]
// energy[b,l] = dot(h[b,:], enc[b,l,:])
//
// Strategy: single fused pass over enc (512 MiB, HBM-bound floor ~85us) using
// online softmax per wave; per-wave partials combined per-block in LDS, then a
// tiny reduce kernel merges chunks. enc is read exactly once.

#define D_DIM 512
#define B_DIM 64
#define L_DIM 4096

__global__ __launch_bounds__(256) void attn_pass1(
    const float* __restrict__ h,      // [B, D]
    const float* __restrict__ enc,    // [B, L, D]
    float* __restrict__ part_ms,      // [B, C, 2]  (m, s)
    float* __restrict__ part_ctx,     // [B, C, D]
    int Cblk)
{
    const int b    = blockIdx.y;
    const int c    = blockIdx.x;
    const int tid  = threadIdx.x;
    const int wave = tid >> 6;
    const int lane = tid & 63;

    const int rowsPerBlock = L_DIM / Cblk;       // e.g. 256
    const int rowsPerWave  = rowsPerBlock >> 2;  // 4 waves/block
    const int l0 = c * rowsPerBlock + wave * rowsPerWave;

    // h fragment: lane covers d = 4*lane..4*lane+3 and 256+4*lane..+3
    const float4* h4 = reinterpret_cast<const float4*>(h + (size_t)b * D_DIM);
    const float4 h0 = h4[lane];
    const float4 h1 = h4[lane + 64];

    const float* rowp = enc + ((size_t)b * L_DIM + (size_t)l0) * D_DIM + 4 * lane;

    float m = -3.0e38f;
    float s = 0.0f;
    float4 a0 = {0.f, 0.f, 0.f, 0.f};
    float4 a1 = {0.f, 0.f, 0.f, 0.f};

    float4 v0 = *reinterpret_cast<const float4*>(rowp);
    float4 v1 = *reinterpret_cast<const float4*>(rowp + 256);

    for (int r = 0; r < rowsPerWave; ++r) {
        // prefetch next row (clamped: last iter re-reads current row, L1-hit)
        const float* np = rowp + ((r + 1 < rowsPerWave) ? D_DIM : 0);
        const float4 nv0 = *reinterpret_cast<const float4*>(np);
        const float4 nv1 = *reinterpret_cast<const float4*>(np + 256);

        float e = h0.x * v0.x + h0.y * v0.y + h0.z * v0.z + h0.w * v0.w
                + h1.x * v1.x + h1.y * v1.y + h1.z * v1.z + h1.w * v1.w;
        #pragma unroll
        for (int off = 32; off > 0; off >>= 1)
            e += __shfl_xor(e, off, 64);
        // e is wave-uniform now; branch below is wave-uniform (taken ~ln(rows) times)
        if (e > m) {
            const float alpha = __expf(m - e);
            s *= alpha;
            a0.x *= alpha; a0.y *= alpha; a0.z *= alpha; a0.w *= alpha;
            a1.x *= alpha; a1.y *= alpha; a1.z *= alpha; a1.w *= alpha;
            m = e;
        }
        const float w = __expf(e - m);
        s += w;
        a0.x += w * v0.x; a0.y += w * v0.y; a0.z += w * v0.z; a0.w += w * v0.w;
        a1.x += w * v1.x; a1.y += w * v1.y; a1.z += w * v1.z; a1.w += w * v1.w;

        v0 = nv0; v1 = nv1;
        rowp += D_DIM;
    }

    // ---- combine the 4 waves of this block in LDS ----
    __shared__ float sm_m[4];
    __shared__ float sm_s[4];
    __shared__ float sm_ctx[4][D_DIM];

    reinterpret_cast<float4*>(&sm_ctx[wave][0])[lane]   = a0;  // d = 4*lane
    reinterpret_cast<float4*>(&sm_ctx[wave][256])[lane] = a1;  // d = 256+4*lane
    if (lane == 0) { sm_m[wave] = m; sm_s[wave] = s; }
    __syncthreads();

    const float M  = fmaxf(fmaxf(sm_m[0], sm_m[1]), fmaxf(sm_m[2], sm_m[3]));
    const float w0 = __expf(sm_m[0] - M);
    const float w1 = __expf(sm_m[1] - M);
    const float w2 = __expf(sm_m[2] - M);
    const float w3 = __expf(sm_m[3] - M);

    if (tid == 0) {
        const float S = sm_s[0] * w0 + sm_s[1] * w1 + sm_s[2] * w2 + sm_s[3] * w3;
        float* ms = part_ms + ((size_t)b * Cblk + c) * 2;
        ms[0] = M;
        ms[1] = S;
    }

    float* dst = part_ctx + ((size_t)b * Cblk + c) * D_DIM;
    for (int d = tid; d < D_DIM; d += 256) {
        dst[d] = sm_ctx[0][d] * w0 + sm_ctx[1][d] * w1
               + sm_ctx[2][d] * w2 + sm_ctx[3][d] * w3;
    }
}

__global__ __launch_bounds__(256) void attn_pass2(
    const float* __restrict__ part_ms,   // [B, C, 2]
    const float* __restrict__ part_ctx,  // [B, C, D]
    float* __restrict__ out,             // [B, D]
    int Cblk, float invL)
{
    const int b   = blockIdx.x;
    const int tid = threadIdx.x;

    __shared__ float w_sm[64];
    __shared__ float invSL;

    if (tid == 0) {
        const float* ms = part_ms + (size_t)b * Cblk * 2;
        float M = -3.0e38f;
        for (int i = 0; i < Cblk; ++i) M = fmaxf(M, ms[2 * i]);
        float S = 0.f;
        for (int i = 0; i < Cblk; ++i) {
            const float w = __expf(ms[2 * i] - M);
            w_sm[i] = w;
            S += w * ms[2 * i + 1];
        }
        invSL = invL / S;
    }
    __syncthreads();

    const float scale = invSL;
    for (int d = tid; d < D_DIM; d += 256) {
        float acc = 0.f;
        for (int i = 0; i < Cblk; ++i)
            acc += w_sm[i] * part_ctx[((size_t)b * Cblk + i) * D_DIM + d];
        out[(size_t)b * D_DIM + d] = acc * scale;
    }
}

extern "C" void kernel_launch(void* const* d_in, const int* in_sizes, int n_in,
                              void* d_out, int out_size, void* d_ws, size_t ws_size,
                              hipStream_t stream) {
    const float* h   = (const float*)d_in[0];  // [B, D]
    const float* enc = (const float*)d_in[1];  // [B, L, D]
    float* out = (float*)d_out;                // [B, D]

    // Chunks per batch: prefer 16 (1024 blocks -> 4 blocks/CU, 2 MiB partials).
    // Fall back to fewer chunks if workspace is tight.
    int C = 16;
    while (C > 1) {
        const size_t need = ((size_t)B_DIM * C * 2 + (size_t)B_DIM * C * D_DIM) * sizeof(float);
        if (need <= ws_size) break;
        C >>= 1;
    }

    float* part_ms  = (float*)d_ws;
    float* part_ctx = part_ms + (size_t)B_DIM * C * 2;  // 16B-aligned (B*C*2*4 bytes)

    dim3 grid1(C, B_DIM);
    attn_pass1<<<grid1, 256, 0, stream>>>(h, enc, part_ms, part_ctx, C);
    attn_pass2<<<B_DIM, 256, 0, stream>>>(part_ms, part_ctx, out, C, 1.0f / (float)L_DIM);
}